// Round 11
// baseline (319.210 us; speedup 1.0000x reference)
//
#include <hip/hip_runtime.h>
#include <hip/hip_bf16.h>

// LSS voxel pooling, segment-bucket variant (no global scan, 3 dispatches).
//   x:    (B=8, N=6, D=41, H=16, W=44, C=64) f32
//   geom: (B, N, D, H, W, 3) f32
//   out:  (B, C=64, X=200, Y=200) f32
//
// bin = (b*200 + ix)*200 + iy,  kept iff 0<=ix<200, 0<=iy<200, iz==0
// (IEEE fp32 add + div + trunc-toward-zero matches reference .astype(int32))
//
// Pipeline (3 dispatches):
//   0 memset     : zero 3200 segment counters (12.8 KB)
//   1 seg_scatter: per kept point, slot = atomicAdd(segcnt[bin/100]);
//                  segbuf[seg*1024+slot] = (pid<<8)|iy%100.  One geom read.
//   2 gather8    : block = segment (100 bins). Counting-sort the segment's
//                  ~341 points by iy in LDS (100 counters + block scan +
//                  LDS list), then quarter-wave float4 equal-split gather:
//                  run-length register accumulation, flush runs via 4 LDS
//                  atomicAdds into a [iy][c] tile (stride 69), coalesced
//                  out-write. Poisson(341) vs cap 1024 => overflow ~30 sigma.

#define NP        1385472
#define NP_PER_B  173184      // N*D*H*W
#define NXY       200
#define NSEG      3200        // 8*200*2 half-row segments (= bin/100)
#define SEGCAP    1024
#define UNR       8           // point-steps in flight per quarter
#define TSTRIDE   69          // tile row stride in floats (odd -> conflict-free)

// ---------------- phase 1: bucket points by segment ----------------
__global__ void seg_scatter(const float* __restrict__ geom,
                            int* __restrict__ segcnt,
                            unsigned int* __restrict__ segbuf) {
    int p = blockIdx.x * 256 + threadIdx.x;
    if (p >= NP) return;
    float gx = geom[(size_t)p * 3 + 0];
    float gy = geom[(size_t)p * 3 + 1];
    float gz = geom[(size_t)p * 3 + 2];
    int ix = (int)((gx + 50.0f) / 0.5f);
    int iy = (int)((gy + 50.0f) / 0.5f);
    int iz = (int)((gz + 10.0f) / 20.0f);
    if (ix >= 0 && ix < NXY && iy >= 0 && iy < NXY && iz == 0) {
        int b   = p / NP_PER_B;
        int bin = (b * NXY + ix) * NXY + iy;
        int seg = bin / 100;
        int slot = atomicAdd(&segcnt[seg], 1);
        if (slot < SEGCAP)   // >30-sigma guard; protects memory, never expected
            segbuf[(size_t)seg * SEGCAP + slot] =
                ((unsigned int)p << 8) | (unsigned int)(iy % 100);
    }
}

// ------- phase 2: per-segment counting sort + quarter-wave float4 gather -------
__global__ __launch_bounds__(256, 4) void gather8(const float* __restrict__ x,
                                                  const int* __restrict__ segcnt,
                                                  const unsigned int* __restrict__ segbuf,
                                                  float* __restrict__ out) {
    __shared__ float        tile[100 * TSTRIDE];  // [iy_local][c]  27.6 KB
    __shared__ unsigned int list[SEGCAP];         // iy-grouped points  4 KB
    __shared__ int          cnt[128];             // histogram / cursors
    __shared__ int          pfx[128];             // inclusive scan tmp

    const int tid = threadIdx.x;
    for (int f = tid; f < 100 * TSTRIDE; f += 256) tile[f] = 0.0f;
    if (tid < 128) cnt[tid] = 0;
    __syncthreads();

    const int seg = blockIdx.x;
    const int n   = min(segcnt[seg], SEGCAP);
    const unsigned int* sb = segbuf + (size_t)seg * SEGCAP;

    if (n > 0) {
        // ---- counting sort by iy_local ----
        for (int i = tid; i < n; i += 256)
            atomicAdd(&cnt[sb[i] & 0xFFu], 1);
        __syncthreads();
        if (tid < 128) pfx[tid] = cnt[tid];
        __syncthreads();
        for (int d = 1; d < 128; d <<= 1) {
            int t = 0;
            if (tid < 128 && tid >= d) t = pfx[tid - d];
            __syncthreads();
            if (tid < 128) pfx[tid] += t;
            __syncthreads();
        }
        if (tid < 128) cnt[tid] = (tid == 0) ? 0 : pfx[tid - 1];  // exclusive -> cursors
        __syncthreads();
        for (int i = tid; i < n; i += 256) {
            const unsigned int pk = sb[i];
            const int pos = atomicAdd(&cnt[pk & 0xFFu], 1);
            list[pos] = pk;
        }
        __syncthreads();

        // ---- equal-split quarter-wave gather over grouped list ----
        const float4* __restrict__ x4 = (const float4*)x;
        const int wave = tid >> 6;
        const int lane = tid & 63;
        const int q    = lane >> 4;          // quarter 0..3
        const int sl   = lane & 15;          // channels 4*sl..4*sl+3
        const int t16  = wave * 4 + q;       // block-quarter 0..15

        const int ps = (n * t16) >> 4;
        const int pe = (n * (t16 + 1)) >> 4;

        int   cur = -1;
        float ax = 0.f, ay = 0.f, az = 0.f, aw = 0.f;

        int i = ps;
        while (__any(i < pe)) {
            unsigned int pk[UNR];
#pragma unroll
            for (int u = 0; u < UNR; ++u) {
                int ii = i + u;
                ii = (ii < pe) ? ii : (pe - 1);
                ii = (ii < 0) ? 0 : ii;
                pk[u] = list[ii < n ? ii : 0];          // clamped LDS read
            }
            float4 v[UNR];
#pragma unroll
            for (int u = 0; u < UNR; ++u) {
                const bool val = (i + u) < pe;
                const unsigned int pid = val ? (pk[u] >> 8) : 0u;
                v[u] = x4[(size_t)pid * 16 + sl];       // UNR x 1KB in flight
            }
#pragma unroll
            for (int u = 0; u < UNR; ++u) {
                const bool val = (i + u) < pe;
                const int iyv  = val ? (int)(pk[u] & 0xFFu) : cur;
                const bool chg = (iyv != cur);
                if (chg && cur >= 0) {                  // flush run (exec-masked)
                    float* dst = &tile[cur * TSTRIDE + 4 * sl];
                    atomicAdd(dst + 0, ax); atomicAdd(dst + 1, ay);
                    atomicAdd(dst + 2, az); atomicAdd(dst + 3, aw);
                }
                const float mx = val ? v[u].x : 0.f;
                const float my = val ? v[u].y : 0.f;
                const float mz = val ? v[u].z : 0.f;
                const float mw = val ? v[u].w : 0.f;
                ax = chg ? v[u].x : ax + mx;            // chg implies val
                ay = chg ? v[u].y : ay + my;
                az = chg ? v[u].z : az + mz;
                aw = chg ? v[u].w : aw + mw;
                cur = chg ? iyv : cur;
            }
            i += UNR;
        }
        if (cur >= 0) {                                 // final flush
            float* dst = &tile[cur * TSTRIDE + 4 * sl];
            atomicAdd(dst + 0, ax); atomicAdd(dst + 1, ay);
            atomicAdd(dst + 2, az); atomicAdd(dst + 3, aw);
        }
    }
    __syncthreads();

    // ---- coalesced out-write ----
    const int b     = seg / 400;           // seg = ((b*200+ix)*2 + half)
    const int ix    = (seg >> 1) % 200;
    const int hbase = (seg & 1) * 100;
    float* obase = out + (size_t)b * 64 * 40000 + (size_t)ix * 200 + hbase;
    for (int f = tid; f < 64 * 100; f += 256) {
        const int c  = f / 100;
        const int iy = f % 100;
        obase[(size_t)c * 40000 + iy] = tile[iy * TSTRIDE + c];
    }
}

// ---------------- fallback (round-1): direct atomic scatter ----------------
__global__ void lss_scatter_atomic(const float* __restrict__ x,
                                   const float* __restrict__ geom,
                                   float* __restrict__ out) {
    const int lane   = threadIdx.x & 63;
    const int wave   = (blockIdx.x * blockDim.x + threadIdx.x) >> 6;
    const int nwaves = (gridDim.x * blockDim.x) >> 6;
    for (int p = wave; p < NP; p += nwaves) {
        const float gx = geom[(size_t)p * 3 + 0];
        const float gy = geom[(size_t)p * 3 + 1];
        const float gz = geom[(size_t)p * 3 + 2];
        const int ix = (int)((gx + 50.0f) / 0.5f);
        const int iy = (int)((gy + 50.0f) / 0.5f);
        const int iz = (int)((gz + 10.0f) / 20.0f);
        if (ix >= 0 && ix < NXY && iy >= 0 && iy < NXY && iz == 0) {
            const int b = p / NP_PER_B;
            const float v = x[(size_t)p * 64 + lane];
            atomicAdd(&out[(((size_t)b * 64 + lane) * NXY + ix) * NXY + iy], v);
        }
    }
}

extern "C" void kernel_launch(void* const* d_in, const int* in_sizes, int n_in,
                              void* d_out, int out_size, void* d_ws, size_t ws_size,
                              hipStream_t stream) {
    const float* x    = (const float*)d_in[0];
    const float* geom = (const float*)d_in[1];
    float* out = (float*)d_out;

    // workspace carve-up
    char* ws = (char*)d_ws;
    size_t off = 0;
    int* segcnt = (int*)(ws + off);          off += (size_t)NSEG * 4;
    unsigned int* segbuf = (unsigned int*)(ws + off);
    off += (size_t)NSEG * SEGCAP * 4;        // 13.1 MB

    if (ws_size < off) {
        // fallback: direct atomic scatter
        hipMemsetAsync(out, 0, (size_t)out_size * sizeof(float), stream);
        lss_scatter_atomic<<<2048, 256, 0, stream>>>(x, geom, out);
        return;
    }

    hipMemsetAsync(segcnt, 0, (size_t)NSEG * 4, stream);

    const int pblocks = (NP + 255) / 256;                 // 5412
    seg_scatter<<<pblocks, 256, 0, stream>>>(geom, segcnt, segbuf);
    gather8<<<NSEG, 256, 0, stream>>>(x, segcnt, segbuf, out);
}

// Round 12
// 185.592 us; speedup vs baseline: 1.7200x; 1.7200x over previous
//
#include <hip/hip_runtime.h>
#include <hip/hip_bf16.h>

// LSS voxel pooling, per-bin bucket variant (no global scan, 3 dispatches).
//   x:    (B=8, N=6, D=41, H=16, W=44, C=64) f32
//   geom: (B, N, D, H, W, 3) f32
//   out:  (B, C=64, X=200, Y=200) f32
//
// bin = (b*200 + ix)*200 + iy,  kept iff 0<=ix<200, 0<=iy<200, iz==0
// (IEEE fp32 add + div + trunc-toward-zero matches reference .astype(int32))
//
// Pipeline (3 dispatches):
//   0 memset        : zero 320K bin counters + overflow counter (1.28 MB)
//   1 bucket_scatter: per kept point, slot = atomicAdd(counts[bin]) (320K
//                     counters -> avg 3.4 hits each, low contention; round-11
//                     showed 3200 counters = 341 hits = 215us disaster);
//                     bucket[bin*32+slot] = pid. Overflow (P ~ 1e-20) goes to
//                     a global list that gather folds in -> always correct.
//   2 gather9       : block = segment (100 consecutive bins = half (b,ix)
//                     row). Read 100 counts, 128-wide LDS scan, rebuild the
//                     bin-grouped point list (coalesced bucket reads, no
//                     atomics, no sort). Quarter-wave float4 gather with
//                     bin-aligned quarter ranges: run-length register
//                     accumulation, ONE plain tile write per non-empty bin,
//                     fold overflow list, coalesced out-write.

#define NP        1385472
#define NP_PER_B  173184      // N*D*H*W
#define NXY       200
#define NBIN      320000      // 8*200*200
#define NSEG      3200        // NBIN/100
#define CAP       32          // bucket capacity per bin (mean 3.4)
#define CAPSH     5
#define OVF_CAP   4096
#define UNR       8           // x-loads in flight per quarter
#define TSTRIDE   69          // tile row stride (odd -> conflict-free)
#define LSIZE     1024        // per-segment list cap (mean 341, 37 sigma)

// ---------------- phase 1: bucket points by bin ----------------
__global__ void bucket_scatter(const float* __restrict__ geom,
                               int* __restrict__ counts,
                               unsigned int* __restrict__ bucket,
                               int* __restrict__ ovf_cnt,
                               int* __restrict__ ovf) {
    int p = blockIdx.x * 256 + threadIdx.x;
    if (p >= NP) return;
    float gx = geom[(size_t)p * 3 + 0];
    float gy = geom[(size_t)p * 3 + 1];
    float gz = geom[(size_t)p * 3 + 2];
    int ix = (int)((gx + 50.0f) / 0.5f);
    int iy = (int)((gy + 50.0f) / 0.5f);
    int iz = (int)((gz + 10.0f) / 20.0f);
    if (ix >= 0 && ix < NXY && iy >= 0 && iy < NXY && iz == 0) {
        int b   = p / NP_PER_B;
        int bin = (b * NXY + ix) * NXY + iy;
        int slot = atomicAdd(&counts[bin], 1);
        if (slot < CAP) {
            bucket[((size_t)bin << CAPSH) + slot] = (unsigned int)p;
        } else {                       // ~1e-20 path; kept for strict correctness
            int o = atomicAdd(ovf_cnt, 1);
            if (o < OVF_CAP) { ovf[2 * o] = p; ovf[2 * o + 1] = bin; }
        }
    }
}

// ------- phase 2: per-segment list rebuild + quarter-wave float4 gather -------
__global__ __launch_bounds__(256, 4) void gather9(const float* __restrict__ x,
                                                  const int* __restrict__ counts,
                                                  const unsigned int* __restrict__ bucket,
                                                  const int* __restrict__ ovf_cnt,
                                                  const int* __restrict__ ovf,
                                                  float* __restrict__ out) {
    __shared__ float        tile[100 * TSTRIDE];  // [iy_local][c]  27.6 KB
    __shared__ unsigned int list[LSIZE];          // bin-grouped (pid<<8|bl)  4 KB
    __shared__ int          cnt[128];             // clamped per-bin counts
    __shared__ int          pfx[128];             // inclusive scan

    const int tid  = threadIdx.x;
    const int seg  = blockIdx.x;
    const int bin0 = seg * 100;

    for (int f = tid; f < 100 * TSTRIDE; f += 256) tile[f] = 0.0f;
    if (tid < 128) {
        int c = (tid < 100) ? min(counts[bin0 + tid], CAP) : 0;
        cnt[tid] = c;
        pfx[tid] = c;
    }
    __syncthreads();
    // inclusive scan over 128
    for (int d = 1; d < 128; d <<= 1) {
        int t = 0;
        if (tid < 128 && tid >= d) t = pfx[tid - d];
        __syncthreads();
        if (tid < 128) pfx[tid] += t;
        __syncthreads();
    }
    // rebuild bin-grouped list (exclusive prefix = pfx[bl]-cnt[bl]); coalesced
    for (int i = tid; i < 100 * CAP; i += 256) {
        const int bl = i >> CAPSH;
        const int s  = i & (CAP - 1);
        if (s < cnt[bl]) {
            const int pos = pfx[bl] - cnt[bl] + s;
            if (pos < LSIZE)
                list[pos] = (bucket[((size_t)(bin0 + bl) << CAPSH) + s] << 8)
                            | (unsigned int)bl;
        }
    }
    __syncthreads();

    // ---- quarter-wave gather, bin-aligned exclusive quarter ranges ----
    const float4* __restrict__ x4 = (const float4*)x;
    const int wave = tid >> 6;
    const int lane = tid & 63;
    const int q    = lane >> 4;          // quarter 0..3
    const int sl   = lane & 15;          // channels 4*sl..4*sl+3
    const int t16  = wave * 4 + q;       // block-quarter 0..15

    // bins [bs, be): quarters 0-3 own 7 bins, 4-15 own 6  (4*7+12*6=100)
    const int bs = (t16 < 4) ? t16 * 7 : 28 + (t16 - 4) * 6;
    const int be = bs + ((t16 < 4) ? 7 : 6);
    int ps = pfx[bs] - cnt[bs];
    int pe = (be < 100) ? (pfx[be] - cnt[be]) : pfx[99];
    ps = min(ps, LSIZE); pe = min(pe, LSIZE);

    int   cur = -1;
    float ax = 0.f, ay = 0.f, az = 0.f, aw = 0.f;

    int i = ps;
    while (__any(i < pe)) {
        unsigned int pk[UNR];
#pragma unroll
        for (int u = 0; u < UNR; ++u) {
            int ii = i + u;
            ii = (ii < pe) ? ii : (pe - 1);
            ii = (ii < 0) ? 0 : ii;
            pk[u] = list[ii];
        }
        float4 v[UNR];
#pragma unroll
        for (int u = 0; u < UNR; ++u) {
            const bool val = (i + u) < pe;
            const unsigned int pid = val ? (pk[u] >> 8) : 0u;
            v[u] = x4[(size_t)pid * 16 + sl];           // UNR x 1KB in flight
        }
#pragma unroll
        for (int u = 0; u < UNR; ++u) {
            const bool val = (i + u) < pe;
            const int iyv  = val ? (int)(pk[u] & 0xFFu) : cur;
            const bool chg = (iyv != cur);
            if (chg && cur >= 0) {       // flush run; bins exclusive -> plain write
                float* dst = &tile[cur * TSTRIDE + 4 * sl];
                dst[0] = ax; dst[1] = ay; dst[2] = az; dst[3] = aw;
            }
            const float mx = val ? v[u].x : 0.f;
            const float my = val ? v[u].y : 0.f;
            const float mz = val ? v[u].z : 0.f;
            const float mw = val ? v[u].w : 0.f;
            ax = chg ? v[u].x : ax + mx;                 // chg implies val
            ay = chg ? v[u].y : ay + my;
            az = chg ? v[u].z : az + mz;
            aw = chg ? v[u].w : aw + mw;
            cur = chg ? iyv : cur;
        }
        i += UNR;
    }
    if (cur >= 0) {
        float* dst = &tile[cur * TSTRIDE + 4 * sl];
        dst[0] = ax; dst[1] = ay; dst[2] = az; dst[3] = aw;
    }
    __syncthreads();

    // ---- fold overflow list (normally empty) ----
    if (wave == 0) {
        const int no = min(*ovf_cnt, OVF_CAP);
        for (int o = 0; o < no; ++o) {
            const int obin = ovf[2 * o + 1];
            if (obin >= bin0 && obin < bin0 + 100)
                tile[(obin - bin0) * TSTRIDE + lane] +=
                    x[(size_t)ovf[2 * o] * 64 + lane];
        }
    }
    __syncthreads();

    // ---- coalesced out-write ----
    const int b     = seg / 400;          // seg = b*400 + ix*2 + half
    const int ix    = (seg >> 1) % 200;
    const int hbase = (seg & 1) * 100;
    float* obase = out + (size_t)b * 64 * 40000 + (size_t)ix * 200 + hbase;
    for (int f = tid; f < 64 * 100; f += 256) {
        const int c  = f / 100;
        const int iy = f % 100;
        obase[(size_t)c * 40000 + iy] = tile[iy * TSTRIDE + c];
    }
}

// ---------------- fallback (round-1): direct atomic scatter ----------------
__global__ void lss_scatter_atomic(const float* __restrict__ x,
                                   const float* __restrict__ geom,
                                   float* __restrict__ out) {
    const int lane   = threadIdx.x & 63;
    const int wave   = (blockIdx.x * blockDim.x + threadIdx.x) >> 6;
    const int nwaves = (gridDim.x * blockDim.x) >> 6;
    for (int p = wave; p < NP; p += nwaves) {
        const float gx = geom[(size_t)p * 3 + 0];
        const float gy = geom[(size_t)p * 3 + 1];
        const float gz = geom[(size_t)p * 3 + 2];
        const int ix = (int)((gx + 50.0f) / 0.5f);
        const int iy = (int)((gy + 50.0f) / 0.5f);
        const int iz = (int)((gz + 10.0f) / 20.0f);
        if (ix >= 0 && ix < NXY && iy >= 0 && iy < NXY && iz == 0) {
            const int b = p / NP_PER_B;
            const float v = x[(size_t)p * 64 + lane];
            atomicAdd(&out[(((size_t)b * 64 + lane) * NXY + ix) * NXY + iy], v);
        }
    }
}

extern "C" void kernel_launch(void* const* d_in, const int* in_sizes, int n_in,
                              void* d_out, int out_size, void* d_ws, size_t ws_size,
                              hipStream_t stream) {
    const float* x    = (const float*)d_in[0];
    const float* geom = (const float*)d_in[1];
    float* out = (float*)d_out;

    // workspace carve-up
    char* ws = (char*)d_ws;
    size_t off = 0;
    int* counts  = (int*)(ws + off); off += (size_t)NBIN * 4;
    int* ovf_cnt = (int*)(ws + off); off += 4;
    int* ovf     = (int*)(ws + off); off += (size_t)OVF_CAP * 2 * 4;
    unsigned int* bucket = (unsigned int*)(ws + off);
    off += ((size_t)NBIN << CAPSH) * 4;      // 41 MB

    if (ws_size < off) {
        // fallback: direct atomic scatter
        hipMemsetAsync(out, 0, (size_t)out_size * sizeof(float), stream);
        lss_scatter_atomic<<<2048, 256, 0, stream>>>(x, geom, out);
        return;
    }

    // zero counts + overflow counter in one call (contiguous)
    hipMemsetAsync(counts, 0, (size_t)NBIN * 4 + 4, stream);

    const int pblocks = (NP + 255) / 256;                 // 5412
    bucket_scatter<<<pblocks, 256, 0, stream>>>(geom, counts, bucket, ovf_cnt, ovf);
    gather9<<<NSEG, 256, 0, stream>>>(x, counts, bucket, ovf_cnt, ovf, out);
}